// Round 5
// baseline (104.947 us; speedup 1.0000x reference)
//
#include <hip/hip_runtime.h>
#include <math.h>

#define NFEAT 256
#define NROWS 65536
#define PCOUNT 4194304
#define CH 512                       // pass1 partial chunks
#define ROWS_PER_BLOCK 128           // NROWS / CH
#define PBLK 64                      // param-reduce blocks appended to pass1 grid
#define F_EPS 5.9604645e-07f         // float32 eps * 5
#define F_LN2 0.69314718056f

#define FAST_LOG2(v) __builtin_log2f(v)   // v_log_f32
#define FAST_EXP2(v) __builtin_exp2f(v)   // v_exp_f32

constexpr double D_HALF_LOG2_2PIE = 0.5 * 2.8378770664093453 / 0.6931471805599453;
constexpr double D_LAMBDA_BITS = 13.287712379549449; // 2*log2(100)

__device__ inline double wave_reduce_add(double v) {
  for (int o = 32; o > 0; o >>= 1) v += __shfl_down(v, o, 64);
  return v;
}

// ---------------------------------------------------------------------------
// Pass 1 (+ overlapped param reduction in blocks >= CH).
// YJ blocks: c in [0,CH): rows [c*128,(c+1)*128), 1024 thr = 4 row-subsets
// of 256 features. Always-general coefficients (handles lambda special cases).
// Work in log2 domain: u2 = log2(1+|x|); y = s*(exp2(a*u2)-1) + tt*u2.
// Partials (coalesced): P1[(c*14 + k)*NFEAT + f], k: 0..5 sum_y, 6..11 sum_y2,
// 12 sum_u2(pos), 13 sum_u2(all).
// ---------------------------------------------------------------------------
__global__ __launch_bounds__(1024, 4) void k_pass1(
    const float* __restrict__ x, const float* __restrict__ lam1,
    const float* __restrict__ lam2, const float* __restrict__ rp,
    const float* __restrict__ params,
    float* __restrict__ P1, double* __restrict__ pSums)
{
  const int c = blockIdx.x;
  const int tid = threadIdx.x;

  if (c >= CH) {
    // ---- parameter tensor partial reduction (memory-bound; overlaps YJ) ----
    __shared__ double lred[2][16];
    const int b = c - CH;
    const float4* p4 = (const float4*)params;
    double s = 0.0, q = 0.0;
    for (int i = b * 1024 + tid; i < PCOUNT / 4; i += PBLK * 1024) {
      float4 v = p4[i];
      s += (double)v.x + (double)v.y + (double)v.z + (double)v.w;
      q += (double)v.x * v.x + (double)v.y * v.y
         + (double)v.z * v.z + (double)v.w * v.w;
    }
    s = wave_reduce_add(s); q = wave_reduce_add(q);
    const int w = tid >> 6;
    if ((tid & 63) == 0) { lred[0][w] = s; lred[1][w] = q; }
    __syncthreads();
    if (tid == 0) {
      double S = 0.0, Q = 0.0;
#pragma unroll
      for (int i = 0; i < 16; ++i) { S += lred[0][i]; Q += lred[1][i]; }
      atomicAdd(&pSums[0], S);
      atomicAdd(&pSums[1], Q);
    }
    return;
  }

  // ---- YJ proposals ----
  __shared__ float red[3][14][NFEAT];
  const int t = tid & 255;
  const int sub = tid >> 8;                  // 0..3
  const int rowsPerThread = ROWS_PER_BLOCK / 4;  // 32

  const float L1 = lam1[t], L2 = lam2[t];
  float a_p[6], a_n[6], s_p[6], s_n[6], t_p[6], t_n[6];
#pragma unroll
  for (int j = 0; j < 6; ++j) {
    float l1 = (j == 0) ? L1 : L1 + 0.1f * rp[t * 10 + 2 * (j - 1)];
    float l2 = (j == 0) ? L2 : L2 + 0.1f * rp[t * 10 + 2 * (j - 1) + 1];
    float tm = 2.0f - l2;
    bool z1 = fabsf(l1) < F_EPS;
    bool z2 = fabsf(l2 - 2.0f) < F_EPS;
    a_p[j] = z1 ? 0.0f : l1;
    s_p[j] = z1 ? 0.0f : 1.0f / l1;
    t_p[j] = z1 ? F_LN2 : 0.0f;
    a_n[j] = z2 ? 0.0f : tm;
    s_n[j] = z2 ? 0.0f : -1.0f / tm;
    t_n[j] = z2 ? -F_LN2 : 0.0f;
  }

  float as[6], aq[6];
#pragma unroll
  for (int j = 0; j < 6; ++j) { as[j] = 0.f; aq[j] = 0.f; }
  float u2p = 0.f, u2a = 0.f;

  const float* xp = x + ((size_t)c * ROWS_PER_BLOCK + sub * rowsPerThread) * NFEAT + t;
#pragma unroll 2
  for (int i = 0; i < rowsPerThread; ++i) {
    float v = xp[(size_t)i * NFEAT];
    bool pos = v >= 0.0f;
    float u2 = FAST_LOG2(1.0f + fabsf(v));
    u2a += u2;
    u2p += pos ? u2 : 0.0f;
#pragma unroll
    for (int j = 0; j < 6; ++j) {
      float a  = pos ? a_p[j] : a_n[j];
      float s  = pos ? s_p[j] : s_n[j];
      float tt = pos ? t_p[j] : t_n[j];
      float e = FAST_EXP2(a * u2);
      float y = fmaf(tt, u2, s * (e - 1.0f));
      as[j] += y;
      aq[j] = fmaf(y, y, aq[j]);
    }
  }

  float acc[14];
#pragma unroll
  for (int j = 0; j < 6; ++j) { acc[j] = as[j]; acc[6 + j] = aq[j]; }
  acc[12] = u2p; acc[13] = u2a;

  if (sub != 0) {
#pragma unroll
    for (int k = 0; k < 14; ++k) red[sub - 1][k][t] = acc[k];
  }
  __syncthreads();
  if (sub == 0) {
#pragma unroll
    for (int k = 0; k < 14; ++k) {
      float a = acc[k] + red[0][k][t] + red[1][k][t] + red[2][k][t];
      P1[((size_t)c * 14 + k) * NFEAT + t] = a;   // coalesced: t contiguous
    }
  }
}

// S[k][f] = sum over c of P1[c][k][f]  (coalesced over f)
__global__ __launch_bounds__(64) void k_reduce_S(
    const float* __restrict__ P1, double* __restrict__ S)
{
  const int k = blockIdx.x >> 2;
  const int f = (blockIdx.x & 3) * 64 + threadIdx.x;
  double acc = 0.0;
  for (int c = 0; c < CH; ++c)
    acc += (double)P1[((size_t)c * 14 + k) * NFEAT + f];
  S[k * NFEAT + f] = acc;
}

// One thread per feature: compute 6 scores in f64, pick min, tie-average.
__global__ __launch_bounds__(256) void k_pick(
    const double* __restrict__ S, const float* __restrict__ lam1,
    const float* __restrict__ lam2, const float* __restrict__ rp,
    float* __restrict__ bestL, int* __restrict__ tied,
    double* __restrict__ bitsF)
{
  const int f = threadIdx.x;
  const double n = (double)NROWS;
  const double sup = S[12 * NFEAT + f];
  const double sun = S[13 * NFEAT + f] - sup;
  const float L1 = lam1[f], L2 = lam2[f];
  double scores[6], al1[6], al2[6];
#pragma unroll
  for (int j = 0; j < 6; ++j) {
    float l1 = (j == 0) ? L1 : L1 + 0.1f * rp[f * 10 + 2 * (j - 1)];
    float l2 = (j == 0) ? L2 : L2 + 0.1f * rp[f * 10 + 2 * (j - 1) + 1];
    al1[j] = (double)l1; al2[j] = (double)l2;
    bool z1 = fabsf(l1) < F_EPS;
    bool z2 = fabsf(l2 - 2.0f) < F_EPS;
    double ccp = z1 ? -1.0 : (double)l1 - 1.0;
    double ccn = z2 ? -1.0 : 1.0 - (double)l2;
    double ljb = ccp * sup + ccn * sun;   // log-jac bits (u2 = bits domain)
    double mean = S[j * NFEAT + f] / n;
    double var = S[(6 + j) * NFEAT + f] / n - mean * mean;
    var = var > 1e-12 ? var : 1e-12;
    scores[j] = n * (D_HALF_LOG2_2PIE + 0.5 * log2(var)) + ljb + D_LAMBDA_BITS;
  }
  double mn = scores[0];
#pragma unroll
  for (int j = 1; j < 6; ++j) mn = scores[j] < mn ? scores[j] : mn;
  double wsum = 0.0, b1 = 0.0, b2 = 0.0;
#pragma unroll
  for (int j = 0; j < 6; ++j) {
    double w = (scores[j] == mn) ? 1.0 : 0.0;
    wsum += w; b1 += w * al1[j]; b2 += w * al2[j];
  }
  bestL[2 * f]     = (float)(b1 / wsum);
  bestL[2 * f + 1] = (float)(b2 / wsum);
  tied[f] = (wsum > 1.5) ? 1 : 0;
  bitsF[f] = mn;   // unique min: identical to re-evaluating at best lambda
}

// Fallback pass 2 (only when some feature tied: averaged lambda is new).
__global__ __launch_bounds__(256) void k_pass2(
    const float* __restrict__ x, const float* __restrict__ bestL,
    const int* __restrict__ tied, float* __restrict__ P2)
{
  __shared__ int any;
  const int t = threadIdx.x;
  if (t == 0) any = 0;
  __syncthreads();
  if (tied[t]) any = 1;
  __syncthreads();
  if (!any) return;

  const int c = blockIdx.x;
  const float l1 = bestL[2 * t], l2 = bestL[2 * t + 1];
  const bool z1 = fabsf(l1) < F_EPS;
  const bool z2 = fabsf(l2 - 2.0f) < F_EPS;
  const float tm = 2.0f - l2;
  const float a_p = z1 ? 0.f : l1,  s_pv = z1 ? 0.f : 1.f / l1,  t_pv = z1 ? F_LN2 : 0.f;
  const float a_n = z2 ? 0.f : tm,  s_nv = z2 ? 0.f : -1.f / tm, t_nv = z2 ? -F_LN2 : 0.f;

  float sy = 0.f, sq = 0.f;
  const float* xp = x + (size_t)c * ROWS_PER_BLOCK * NFEAT + t;
  for (int i = 0; i < ROWS_PER_BLOCK; ++i) {
    float v = xp[(size_t)i * NFEAT];
    bool pos = v >= 0.0f;
    float u2 = FAST_LOG2(1.0f + fabsf(v));
    float a = pos ? a_p : a_n;
    float s = pos ? s_pv : s_nv;
    float tt = pos ? t_pv : t_nv;
    float e = FAST_EXP2(a * u2);
    float y = fmaf(tt, u2, s * (e - 1.0f));
    sy += y;
    sq = fmaf(y, y, sq);
  }
  P2[((size_t)c * 2 + 0) * NFEAT + t] = sy;
  P2[((size_t)c * 2 + 1) * NFEAT + t] = sq;
}

__global__ __launch_bounds__(64) void k_featbits(
    const float* __restrict__ P1, const float* __restrict__ P2,
    const float* __restrict__ bestL, const int* __restrict__ tied,
    double* __restrict__ bitsF)
{
  const int f = blockIdx.x;
  if (!tied[f]) return;
  const int lane = threadIdx.x;
  double s0 = 0.0, s1 = 0.0, sup = 0.0, sua = 0.0;
  for (int c = lane; c < CH; c += 64) {
    s0  += (double)P2[((size_t)c * 2 + 0) * NFEAT + f];
    s1  += (double)P2[((size_t)c * 2 + 1) * NFEAT + f];
    sup += (double)P1[((size_t)c * 14 + 12) * NFEAT + f];
    sua += (double)P1[((size_t)c * 14 + 13) * NFEAT + f];
  }
  s0 = wave_reduce_add(s0); s1 = wave_reduce_add(s1);
  sup = wave_reduce_add(sup); sua = wave_reduce_add(sua);
  if (lane == 0) {
    const float l1 = bestL[2 * f], l2 = bestL[2 * f + 1];
    bool z1 = fabsf(l1) < F_EPS;
    bool z2 = fabsf(l2 - 2.0f) < F_EPS;
    double ccp = z1 ? -1.0 : (double)l1 - 1.0;
    double ccn = z2 ? -1.0 : 1.0 - (double)l2;
    double ljb = ccp * sup + ccn * (sua - sup);
    const double n = (double)NROWS;
    double mean = s0 / n;
    double var = s1 / n - mean * mean;
    var = var > 1e-12 ? var : 1e-12;
    bitsF[f] = n * (D_HALF_LOG2_2PIE + 0.5 * log2(var)) + ljb + D_LAMBDA_BITS;
  }
}

__global__ __launch_bounds__(256) void k_final(
    const double* __restrict__ bitsF, const double* __restrict__ pSums,
    float* __restrict__ out)
{
  __shared__ double l[4];
  double s = bitsF[threadIdx.x];
  s = wave_reduce_add(s);
  int w = threadIdx.x >> 6;
  if ((threadIdx.x & 63) == 0) l[w] = s;
  __syncthreads();
  if (threadIdx.x == 0) {
    double data = l[0] + l[1] + l[2] + l[3];
    const double n = (double)PCOUNT;
    double mean = pSums[0] / n;
    double var = pSums[1] / n - mean * mean;
    var = var > 1e-12 ? var : 1e-12;
    double model = n * (D_HALF_LOG2_2PIE + 0.5 * log2(var)) + D_LAMBDA_BITS;
    out[0] = (float)(data + model);
  }
}

extern "C" void kernel_launch(void* const* d_in, const int* in_sizes, int n_in,
                              void* d_out, int out_size, void* d_ws, size_t ws_size,
                              hipStream_t stream)
{
  const float* x      = (const float*)d_in[0];
  const float* lam1   = (const float*)d_in[1];
  const float* lam2   = (const float*)d_in[2];
  const float* rp     = (const float*)d_in[3];
  const float* params = (const float*)d_in[4];

  char* ws = (char*)d_ws;
  double* pSums = (double*)ws;                  // 16 B          -> 16
  float*  bestL = (float*)(ws + 16);            // 2048 B        -> 2064
  double* bitsF = (double*)(ws + 2064);         // 2048 B        -> 4112
  int*    tied  = (int*)(ws + 4112);            // 1024 B        -> 5136
  double* S     = (double*)(ws + 5136);         // 14*256*8 B    -> 33808
  float*  P1    = (float*)(ws + 33808);         // 512*14*256*4  -> 7373840
  float*  P2    = (float*)(ws + 7373840);       // 512*2*256*4   -> 8422416

  (void)hipMemsetAsync(pSums, 0, 16, stream);
  k_pass1<<<CH + PBLK, 1024, 0, stream>>>(x, lam1, lam2, rp, params, P1, pSums);
  k_reduce_S<<<56, 64, 0, stream>>>(P1, S);
  k_pick<<<1, 256, 0, stream>>>(S, lam1, lam2, rp, bestL, tied, bitsF);
  k_pass2<<<CH, 256, 0, stream>>>(x, bestL, tied, P2);
  k_featbits<<<NFEAT, 64, 0, stream>>>(P1, P2, bestL, tied, bitsF);
  k_final<<<1, 256, 0, stream>>>(bitsF, pSums, (float*)d_out);
}

// Round 7
// 96.868 us; speedup vs baseline: 1.0834x; 1.0834x over previous
//
#include <hip/hip_runtime.h>
#include <math.h>

#define NFEAT 256
#define NROWS 65536
#define PCOUNT 4194304
#define PBLK 64                      // param-reduce blocks appended to pass1 grid
#define CH2 512                      // pass2 fallback chunks
#define F_EPS 5.9604645e-07f         // float32 eps * 5
#define F_LN2 0.69314718056f

#define FAST_LOG2(v) __builtin_log2f(v)   // v_log_f32
#define FAST_EXP2(v) __builtin_exp2f(v)   // v_exp_f32

constexpr double D_HALF_LOG2_2PIE = 0.5 * 2.8378770664093453 / 0.6931471805599453;
constexpr double D_LAMBDA_BITS = 13.287712379549449; // 2*log2(100)

__device__ inline double wave_reduce_add(double v) {
  for (int o = 32; o > 0; o >>= 1) v += __shfl_down(v, o, 64);
  return v;
}

// flag=1 if no lambda proposal hits the special cases (|l1|<eps or |l2-2|<eps).
// Also zeroes pSums (replaces hipMemsetAsync).
__global__ __launch_bounds__(256) void k_precheck(
    const float* __restrict__ lam1, const float* __restrict__ lam2,
    const float* __restrict__ rp, int* __restrict__ flag,
    double* __restrict__ pSums)
{
  __shared__ int bad;
  const int t = threadIdx.x;
  if (t == 0) bad = 0;
  if (t < 2) pSums[t] = 0.0;
  __syncthreads();
  const float L1 = lam1[t], L2 = lam2[t];
  bool b = false;
#pragma unroll
  for (int j = 0; j < 6; ++j) {
    float l1 = (j == 0) ? L1 : L1 + 0.1f * rp[t * 10 + 2 * (j - 1)];
    float l2 = (j == 0) ? L2 : L2 + 0.1f * rp[t * 10 + 2 * (j - 1) + 1];
    b = b || (fabsf(l1) < F_EPS) || (fabsf(l2 - 2.0f) < F_EPS);
  }
  if (b) bad = 1;  // benign same-value race
  __syncthreads();
  if (t == 0) *flag = bad ? 0 : 1;
}

// ---------------------------------------------------------------------------
// Pass 1: blocks [0,CHv): thread t = feature t, rows [c*rpt, (c+1)*rpt).
// No LDS, no barrier. Simple path (flag=1): 4-row unrolled, minimal VALU.
// Partials: P1[(c*14+k)*NFEAT+f]; k 0..5 sum_y, 6..11 sum_y2,
// 12 sum_u2(pos), 13 sum_u2(all); u2 = log2(1+|x|).
// Blocks >= CHv: parameter tensor reduction (overlapped, memory-bound).
// ---------------------------------------------------------------------------
__global__ __launch_bounds__(256, 4) void k_pass1(
    const float* __restrict__ x, const float* __restrict__ lam1,
    const float* __restrict__ lam2, const float* __restrict__ rp,
    const float* __restrict__ params, float* __restrict__ P1,
    double* __restrict__ pSums, const int* __restrict__ flag,
    int CHv, int rpt)
{
  const int c = blockIdx.x;
  const int t = threadIdx.x;

  if (c >= CHv) {
    // ---- parameter tensor partial reduction ----
    __shared__ double lred[2][4];
    const int b = c - CHv;
    const float4* p4 = (const float4*)params;
    double s = 0.0, q = 0.0;
    for (int i = b * 256 + t; i < PCOUNT / 4; i += PBLK * 256) {
      float4 v = p4[i];
      s += (double)v.x + (double)v.y + (double)v.z + (double)v.w;
      q += (double)v.x * v.x + (double)v.y * v.y
         + (double)v.z * v.z + (double)v.w * v.w;
    }
    s = wave_reduce_add(s); q = wave_reduce_add(q);
    const int w = t >> 6;
    if ((t & 63) == 0) { lred[0][w] = s; lred[1][w] = q; }
    __syncthreads();
    if (t == 0) {
      atomicAdd(&pSums[0], lred[0][0] + lred[0][1] + lred[0][2] + lred[0][3]);
      atomicAdd(&pSums[1], lred[1][0] + lred[1][1] + lred[1][2] + lred[1][3]);
    }
    return;
  }

  const float L1 = lam1[t], L2 = lam2[t];
  float a_p[6], a_n[6], s_p[6], s_n[6];
#pragma unroll
  for (int j = 0; j < 6; ++j) {
    float l1 = (j == 0) ? L1 : L1 + 0.1f * rp[t * 10 + 2 * (j - 1)];
    float l2 = (j == 0) ? L2 : L2 + 0.1f * rp[t * 10 + 2 * (j - 1) + 1];
    a_p[j] = l1;
    a_n[j] = 2.0f - l2;
    s_p[j] = 1.0f / a_p[j];      // safe: simple path guarantees |l1|>=eps
    s_n[j] = -1.0f / a_n[j];
  }

  float as[6], aq[6];
#pragma unroll
  for (int j = 0; j < 6; ++j) { as[j] = 0.f; aq[j] = 0.f; }
  float u2p = 0.f, u2a = 0.f;
  const float* xp = x + (size_t)c * rpt * NFEAT + t;

  if (*flag) {
    // ---- simple path: 4-row groups, 24 independent exp chains/group ----
    for (int i = 0; i < rpt; i += 4) {
      float u[4]; bool pos[4];
#pragma unroll
      for (int r = 0; r < 4; ++r) {
        float v = xp[(size_t)(i + r) * NFEAT];
        pos[r] = v >= 0.0f;
        u[r] = FAST_LOG2(1.0f + fabsf(v));
        u2a += u[r];
        u2p += pos[r] ? u[r] : 0.0f;
      }
#pragma unroll
      for (int j = 0; j < 6; ++j) {
#pragma unroll
        for (int r = 0; r < 4; ++r) {
          float a = pos[r] ? a_p[j] : a_n[j];
          float s = pos[r] ? s_p[j] : s_n[j];
          float e = FAST_EXP2(a * u[r]);
          float y = fmaf(s, e, -s);    // s*(e-1)
          as[j] += y;
          aq[j] = fmaf(y, y, aq[j]);
        }
      }
    }
  } else {
    // ---- general path (lambda special cases); 1-row loop, low pressure ----
    float ga_p[6], ga_n[6], gs_p[6], gs_n[6], gt_p[6], gt_n[6];
#pragma unroll
    for (int j = 0; j < 6; ++j) {
      float l1 = a_p[j];
      float tm = a_n[j];
      bool z1 = fabsf(l1) < F_EPS;
      bool z2 = fabsf(tm) < F_EPS;
      ga_p[j] = z1 ? 0.0f : l1;
      gs_p[j] = z1 ? 0.0f : 1.0f / l1;
      gt_p[j] = z1 ? F_LN2 : 0.0f;
      ga_n[j] = z2 ? 0.0f : tm;
      gs_n[j] = z2 ? 0.0f : -1.0f / tm;
      gt_n[j] = z2 ? -F_LN2 : 0.0f;
    }
    for (int i = 0; i < rpt; ++i) {
      float v = xp[(size_t)i * NFEAT];
      bool pos = v >= 0.0f;
      float u2 = FAST_LOG2(1.0f + fabsf(v));
      u2a += u2;
      u2p += pos ? u2 : 0.0f;
#pragma unroll
      for (int j = 0; j < 6; ++j) {
        float a  = pos ? ga_p[j] : ga_n[j];
        float s  = pos ? gs_p[j] : gs_n[j];
        float tt = pos ? gt_p[j] : gt_n[j];
        float e = FAST_EXP2(a * u2);
        float y = fmaf(tt, u2, fmaf(s, e, -s));
        as[j] += y;
        aq[j] = fmaf(y, y, aq[j]);
      }
    }
  }

#pragma unroll
  for (int j = 0; j < 6; ++j) {
    P1[((size_t)c * 14 + j) * NFEAT + t]     = as[j];
    P1[((size_t)c * 14 + 6 + j) * NFEAT + t] = aq[j];
  }
  P1[((size_t)c * 14 + 12) * NFEAT + t] = u2p;
  P1[((size_t)c * 14 + 13) * NFEAT + t] = u2a;
}

// Stage A reduce: block (k, cg): S2[(k*8+cg)*NFEAT+f] = sum over c-subrange.
__global__ __launch_bounds__(256) void k_reduce_S(
    const float* __restrict__ P1, double* __restrict__ S2, int CHv)
{
  const int k = blockIdx.x >> 3;
  const int cg = blockIdx.x & 7;
  const int f = threadIdx.x;
  const int per = CHv >> 3;
  double acc = 0.0;
  for (int c = cg * per; c < (cg + 1) * per; ++c)
    acc += (double)P1[((size_t)c * 14 + k) * NFEAT + f];
  S2[((size_t)k * 8 + cg) * NFEAT + f] = acc;
}

// One thread per feature: 6 scores in f64, min, tie-average.
__global__ __launch_bounds__(256) void k_pick(
    const double* __restrict__ S2, const float* __restrict__ lam1,
    const float* __restrict__ lam2, const float* __restrict__ rp,
    float* __restrict__ bestL, int* __restrict__ tied,
    double* __restrict__ bitsF)
{
  const int f = threadIdx.x;
  double s[14];
#pragma unroll
  for (int k = 0; k < 14; ++k) {
    double a = 0.0;
#pragma unroll
    for (int cg = 0; cg < 8; ++cg)
      a += S2[((size_t)k * 8 + cg) * NFEAT + f];
    s[k] = a;
  }
  const double n = (double)NROWS;
  const double sup = s[12];
  const double sun = s[13] - s[12];
  const float L1 = lam1[f], L2 = lam2[f];
  double scores[6], al1[6], al2[6];
#pragma unroll
  for (int j = 0; j < 6; ++j) {
    float l1 = (j == 0) ? L1 : L1 + 0.1f * rp[f * 10 + 2 * (j - 1)];
    float l2 = (j == 0) ? L2 : L2 + 0.1f * rp[f * 10 + 2 * (j - 1) + 1];
    al1[j] = (double)l1; al2[j] = (double)l2;
    bool z1 = fabsf(l1) < F_EPS;
    bool z2 = fabsf(l2 - 2.0f) < F_EPS;
    double ccp = z1 ? -1.0 : (double)l1 - 1.0;
    double ccn = z2 ? -1.0 : 1.0 - (double)l2;
    double ljb = ccp * sup + ccn * sun;
    double mean = s[j] / n;
    double var = s[6 + j] / n - mean * mean;
    var = var > 1e-12 ? var : 1e-12;
    scores[j] = n * (D_HALF_LOG2_2PIE + 0.5 * log2(var)) + ljb + D_LAMBDA_BITS;
  }
  double mn = scores[0];
#pragma unroll
  for (int j = 1; j < 6; ++j) mn = scores[j] < mn ? scores[j] : mn;
  double wsum = 0.0, b1 = 0.0, b2 = 0.0;
#pragma unroll
  for (int j = 0; j < 6; ++j) {
    double w = (scores[j] == mn) ? 1.0 : 0.0;
    wsum += w; b1 += w * al1[j]; b2 += w * al2[j];
  }
  bestL[2 * f]     = (float)(b1 / wsum);
  bestL[2 * f + 1] = (float)(b2 / wsum);
  tied[f] = (wsum > 1.5) ? 1 : 0;
  bitsF[f] = mn;   // unique min: identical to re-evaluating at best lambda
}

// Fallback pass 2 (only if some feature tied: averaged lambda is new).
__global__ __launch_bounds__(256) void k_pass2(
    const float* __restrict__ x, const float* __restrict__ bestL,
    const int* __restrict__ tied, float* __restrict__ P2)
{
  __shared__ int any;
  const int t = threadIdx.x;
  if (t == 0) any = 0;
  __syncthreads();
  if (tied[t]) any = 1;
  __syncthreads();
  if (!any) return;

  const int c = blockIdx.x;
  const int rpt = NROWS / CH2;   // 128
  const float l1 = bestL[2 * t], l2 = bestL[2 * t + 1];
  const bool z1 = fabsf(l1) < F_EPS;
  const bool z2 = fabsf(l2 - 2.0f) < F_EPS;
  const float tm = 2.0f - l2;
  const float a_p = z1 ? 0.f : l1,  s_pv = z1 ? 0.f : 1.f / l1,  t_pv = z1 ? F_LN2 : 0.f;
  const float a_n = z2 ? 0.f : tm,  s_nv = z2 ? 0.f : -1.f / tm, t_nv = z2 ? -F_LN2 : 0.f;

  float sy = 0.f, sq = 0.f;
  const float* xp = x + (size_t)c * rpt * NFEAT + t;
  for (int i = 0; i < rpt; ++i) {
    float v = xp[(size_t)i * NFEAT];
    bool pos = v >= 0.0f;
    float u2 = FAST_LOG2(1.0f + fabsf(v));
    float a  = pos ? a_p : a_n;
    float s  = pos ? s_pv : s_nv;
    float tt = pos ? t_pv : t_nv;
    float e = FAST_EXP2(a * u2);
    float y = fmaf(tt, u2, fmaf(s, e, -s));
    sy += y;
    sq = fmaf(y, y, sq);
  }
  P2[((size_t)c * 2 + 0) * NFEAT + t] = sy;
  P2[((size_t)c * 2 + 1) * NFEAT + t] = sq;
}

__global__ __launch_bounds__(64) void k_featbits(
    const float* __restrict__ P1, const float* __restrict__ P2,
    const float* __restrict__ bestL, const int* __restrict__ tied,
    double* __restrict__ bitsF, int CHv)
{
  const int f = blockIdx.x;
  if (!tied[f]) return;
  const int lane = threadIdx.x;
  double s0 = 0.0, s1 = 0.0, sup = 0.0, sua = 0.0;
  for (int c = lane; c < CH2; c += 64) {
    s0 += (double)P2[((size_t)c * 2 + 0) * NFEAT + f];
    s1 += (double)P2[((size_t)c * 2 + 1) * NFEAT + f];
  }
  for (int c = lane; c < CHv; c += 64) {
    sup += (double)P1[((size_t)c * 14 + 12) * NFEAT + f];
    sua += (double)P1[((size_t)c * 14 + 13) * NFEAT + f];
  }
  s0 = wave_reduce_add(s0); s1 = wave_reduce_add(s1);
  sup = wave_reduce_add(sup); sua = wave_reduce_add(sua);
  if (lane == 0) {
    const float l1 = bestL[2 * f], l2 = bestL[2 * f + 1];
    bool z1 = fabsf(l1) < F_EPS;
    bool z2 = fabsf(l2 - 2.0f) < F_EPS;
    double ccp = z1 ? -1.0 : (double)l1 - 1.0;
    double ccn = z2 ? -1.0 : 1.0 - (double)l2;
    double ljb = ccp * sup + ccn * (sua - sup);
    const double n = (double)NROWS;
    double mean = s0 / n;
    double var = s1 / n - mean * mean;
    var = var > 1e-12 ? var : 1e-12;
    bitsF[f] = n * (D_HALF_LOG2_2PIE + 0.5 * log2(var)) + ljb + D_LAMBDA_BITS;
  }
}

__global__ __launch_bounds__(256) void k_final(
    const double* __restrict__ bitsF, const double* __restrict__ pSums,
    float* __restrict__ out)
{
  __shared__ double l[4];
  double s = bitsF[threadIdx.x];
  s = wave_reduce_add(s);
  int w = threadIdx.x >> 6;
  if ((threadIdx.x & 63) == 0) l[w] = s;
  __syncthreads();
  if (threadIdx.x == 0) {
    double data = l[0] + l[1] + l[2] + l[3];
    const double n = (double)PCOUNT;
    double mean = pSums[0] / n;
    double var = pSums[1] / n - mean * mean;
    var = var > 1e-12 ? var : 1e-12;
    double model = n * (D_HALF_LOG2_2PIE + 0.5 * log2(var)) + D_LAMBDA_BITS;
    out[0] = (float)(data + model);
  }
}

extern "C" void kernel_launch(void* const* d_in, const int* in_sizes, int n_in,
                              void* d_out, int out_size, void* d_ws, size_t ws_size,
                              hipStream_t stream)
{
  const float* x      = (const float*)d_in[0];
  const float* lam1   = (const float*)d_in[1];
  const float* lam2   = (const float*)d_in[2];
  const float* rp     = (const float*)d_in[3];
  const float* params = (const float*)d_in[4];

  char* ws = (char*)d_ws;
  double* pSums = (double*)ws;                  // 16 B   -> 16
  float*  bestL = (float*)(ws + 16);            // 2048   -> 2064
  double* bitsF = (double*)(ws + 2064);         // 2048   -> 4112
  int*    tied  = (int*)(ws + 4112);            // 1024   -> 5136
  int*    flag  = (int*)(ws + 5136);            // 4      -> pad 5152
  double* S2    = (double*)(ws + 5152);         // 14*8*256*8 = 229376 -> 234528
  float*  P1    = (float*)(ws + 234528);

  // adaptive chunk count: prefer CH=1024
  int CHv = 1024;
  while (CHv > 256) {
    size_t need = 234528 + (size_t)CHv * 14 * NFEAT * 4
                         + (size_t)CH2 * 2 * NFEAT * 4;
    if (need <= ws_size) break;
    CHv >>= 1;
  }
  float* P2 = (float*)(ws + 234528 + (size_t)CHv * 14 * NFEAT * 4);
  int rpt = NROWS / CHv;

  k_precheck<<<1, 256, 0, stream>>>(lam1, lam2, rp, flag, pSums);
  k_pass1<<<CHv + PBLK, 256, 0, stream>>>(x, lam1, lam2, rp, params, P1,
                                          pSums, flag, CHv, rpt);
  k_reduce_S<<<112, 256, 0, stream>>>(P1, S2, CHv);
  k_pick<<<1, 256, 0, stream>>>(S2, lam1, lam2, rp, bestL, tied, bitsF);
  k_pass2<<<CH2, 256, 0, stream>>>(x, bestL, tied, P2);
  k_featbits<<<NFEAT, 64, 0, stream>>>(P1, P2, bestL, tied, bitsF, CHv);
  k_final<<<1, 256, 0, stream>>>(bitsF, pSums, (float*)d_out);
}

// Round 8
// 90.404 us; speedup vs baseline: 1.1609x; 1.0715x over previous
//
#include <hip/hip_runtime.h>
#include <math.h>

#define NFEAT 256
#define NROWS 65536
#define PCOUNT 4194304
#define CH2 512                      // pass2 fallback chunks
#define RGRP 8                       // reduce_S c-groups
#define F_EPS 5.9604645e-07f         // float32 eps * 5
#define F_LN2 0.69314718056f

#define FAST_LOG2(v) __builtin_log2f(v)   // v_log_f32
#define FAST_EXP2(v) __builtin_exp2f(v)   // v_exp_f32

constexpr double D_HALF_LOG2_2PIE = 0.5 * 2.8378770664093453 / 0.6931471805599453;
constexpr double D_LAMBDA_BITS = 13.287712379549449; // 2*log2(100)

__device__ inline double wave_reduce_add(double v) {
  for (int o = 32; o > 0; o >>= 1) v += __shfl_down(v, o, 64);
  return v;
}

// ---------------------------------------------------------------------------
// Pass 1: grid = CHv blocks of 256 (exactly 4 blocks/CU at CHv=1024).
// Each block: (a) local precheck flag; (b) YJ rows [c*rpt,(c+1)*rpt),
// thread t = feature t, 8-row groups (48 indep exp chains); (c) grid-strided
// slice of the parameter tensor reduction.
// Partials: P1[(c*14+k)*NFEAT+f]; k 0..5 sum_y, 6..11 sum_y2,
// 12 sum_u2(pos), 13 sum_u2(all); u2 = log2(1+|x|).
// ---------------------------------------------------------------------------
__global__ __launch_bounds__(256, 4) void k_pass1(
    const float* __restrict__ x, const float* __restrict__ lam1,
    const float* __restrict__ lam2, const float* __restrict__ rp,
    const float* __restrict__ params, float* __restrict__ P1,
    double* __restrict__ pSums, int CHv, int rpt)
{
  const int c = blockIdx.x;
  const int t = threadIdx.x;
  __shared__ int bad;
  __shared__ double lred[2][4];

  if (t == 0) bad = 0;
  __syncthreads();

  const float L1 = lam1[t], L2 = lam2[t];
  float l1v[6], l2v[6];
  bool b = false;
#pragma unroll
  for (int j = 0; j < 6; ++j) {
    l1v[j] = (j == 0) ? L1 : L1 + 0.1f * rp[t * 10 + 2 * (j - 1)];
    l2v[j] = (j == 0) ? L2 : L2 + 0.1f * rp[t * 10 + 2 * (j - 1) + 1];
    b = b || (fabsf(l1v[j]) < F_EPS) || (fabsf(l2v[j] - 2.0f) < F_EPS);
  }
  if (b) bad = 1;  // benign same-value race
  __syncthreads();

  float as[6], aq[6];
#pragma unroll
  for (int j = 0; j < 6; ++j) { as[j] = 0.f; aq[j] = 0.f; }
  float u2p = 0.f, u2a = 0.f;
  const float* xp = x + (size_t)c * rpt * NFEAT + t;

  if (bad == 0) {
    // ---- simple path ----
    float a_p[6], a_n[6], s_p[6], s_n[6];
#pragma unroll
    for (int j = 0; j < 6; ++j) {
      a_p[j] = l1v[j];
      a_n[j] = 2.0f - l2v[j];
      s_p[j] = 1.0f / a_p[j];
      s_n[j] = -1.0f / a_n[j];
      // pin in VGPRs: block rematerialization (esp. v_rcp) in the hot loop
      asm volatile("" : "+v"(a_p[j]), "+v"(a_n[j]), "+v"(s_p[j]), "+v"(s_n[j]));
    }
    for (int i = 0; i < rpt; i += 8) {
      float u[8]; bool pos[8];
#pragma unroll
      for (int r = 0; r < 8; ++r) {
        float v = xp[(size_t)(i + r) * NFEAT];
        pos[r] = v >= 0.0f;
        u[r] = FAST_LOG2(1.0f + fabsf(v));
        u2a += u[r];
        u2p += pos[r] ? u[r] : 0.0f;
      }
#pragma unroll
      for (int j = 0; j < 6; ++j) {
#pragma unroll
        for (int r = 0; r < 8; ++r) {
          float a = pos[r] ? a_p[j] : a_n[j];
          float s = pos[r] ? s_p[j] : s_n[j];
          float e = FAST_EXP2(a * u[r]);
          float y = fmaf(s, e, -s);    // s*(e-1)
          as[j] += y;
          aq[j] = fmaf(y, y, aq[j]);
        }
      }
    }
  } else {
    // ---- general path (lambda special cases) ----
    float ga_p[6], ga_n[6], gs_p[6], gs_n[6], gt_p[6], gt_n[6];
#pragma unroll
    for (int j = 0; j < 6; ++j) {
      float l1 = l1v[j];
      float tm = 2.0f - l2v[j];
      bool z1 = fabsf(l1) < F_EPS;
      bool z2 = fabsf(tm) < F_EPS;
      ga_p[j] = z1 ? 0.0f : l1;
      gs_p[j] = z1 ? 0.0f : 1.0f / l1;
      gt_p[j] = z1 ? F_LN2 : 0.0f;
      ga_n[j] = z2 ? 0.0f : tm;
      gs_n[j] = z2 ? 0.0f : -1.0f / tm;
      gt_n[j] = z2 ? -F_LN2 : 0.0f;
    }
    for (int i = 0; i < rpt; ++i) {
      float v = xp[(size_t)i * NFEAT];
      bool pos = v >= 0.0f;
      float u2 = FAST_LOG2(1.0f + fabsf(v));
      u2a += u2;
      u2p += pos ? u2 : 0.0f;
#pragma unroll
      for (int j = 0; j < 6; ++j) {
        float a  = pos ? ga_p[j] : ga_n[j];
        float s  = pos ? gs_p[j] : gs_n[j];
        float tt = pos ? gt_p[j] : gt_n[j];
        float e = FAST_EXP2(a * u2);
        float y = fmaf(tt, u2, fmaf(s, e, -s));
        as[j] += y;
        aq[j] = fmaf(y, y, aq[j]);
      }
    }
  }

#pragma unroll
  for (int j = 0; j < 6; ++j) {
    P1[((size_t)c * 14 + j) * NFEAT + t]     = as[j];
    P1[((size_t)c * 14 + 6 + j) * NFEAT + t] = aq[j];
  }
  P1[((size_t)c * 14 + 12) * NFEAT + t] = u2p;
  P1[((size_t)c * 14 + 13) * NFEAT + t] = u2a;

  // ---- parameter tensor partial reduction (grid-strided epilogue) ----
  {
    const float4* p4 = (const float4*)params;
    double s = 0.0, q = 0.0;
    for (int i = c * 256 + t; i < PCOUNT / 4; i += CHv * 256) {
      float4 v = p4[i];
      s += (double)v.x + (double)v.y + (double)v.z + (double)v.w;
      q += (double)v.x * v.x + (double)v.y * v.y
         + (double)v.z * v.z + (double)v.w * v.w;
    }
    s = wave_reduce_add(s); q = wave_reduce_add(q);
    const int w = t >> 6;
    if ((t & 63) == 0) { lred[0][w] = s; lred[1][w] = q; }
    __syncthreads();
    if (t == 0) {
      atomicAdd(&pSums[0], lred[0][0] + lred[0][1] + lred[0][2] + lred[0][3]);
      atomicAdd(&pSums[1], lred[1][0] + lred[1][1] + lred[1][2] + lred[1][3]);
    }
  }
}

// Stage A reduce: block (k, cg): S2[(k*RGRP+cg)*NFEAT+f] = sum over c-subrange.
// 4 independent accumulators break the dependent-add chain.
__global__ __launch_bounds__(256) void k_reduce_S(
    const float* __restrict__ P1, double* __restrict__ S2, int CHv)
{
  const int k = blockIdx.x / RGRP;
  const int cg = blockIdx.x % RGRP;
  const int f = threadIdx.x;
  const int per = CHv / RGRP;
  const int c0 = cg * per;
  double a0 = 0.0, a1 = 0.0, a2 = 0.0, a3 = 0.0;
  for (int c = c0; c < c0 + per; c += 4) {
    a0 += (double)P1[((size_t)(c + 0) * 14 + k) * NFEAT + f];
    a1 += (double)P1[((size_t)(c + 1) * 14 + k) * NFEAT + f];
    a2 += (double)P1[((size_t)(c + 2) * 14 + k) * NFEAT + f];
    a3 += (double)P1[((size_t)(c + 3) * 14 + k) * NFEAT + f];
  }
  S2[((size_t)k * RGRP + cg) * NFEAT + f] = (a0 + a1) + (a2 + a3);
}

// One thread per feature: 6 scores in f64, min, tie-average.
__global__ __launch_bounds__(256) void k_pick(
    const double* __restrict__ S2, const float* __restrict__ lam1,
    const float* __restrict__ lam2, const float* __restrict__ rp,
    float* __restrict__ bestL, int* __restrict__ tied,
    double* __restrict__ bitsF)
{
  const int f = threadIdx.x;
  double s[14];
#pragma unroll
  for (int k = 0; k < 14; ++k) {
    double a = 0.0;
#pragma unroll
    for (int cg = 0; cg < RGRP; ++cg)
      a += S2[((size_t)k * RGRP + cg) * NFEAT + f];
    s[k] = a;
  }
  const double n = (double)NROWS;
  const double sup = s[12];
  const double sun = s[13] - s[12];
  const float L1 = lam1[f], L2 = lam2[f];
  double scores[6], al1[6], al2[6];
#pragma unroll
  for (int j = 0; j < 6; ++j) {
    float l1 = (j == 0) ? L1 : L1 + 0.1f * rp[f * 10 + 2 * (j - 1)];
    float l2 = (j == 0) ? L2 : L2 + 0.1f * rp[f * 10 + 2 * (j - 1) + 1];
    al1[j] = (double)l1; al2[j] = (double)l2;
    bool z1 = fabsf(l1) < F_EPS;
    bool z2 = fabsf(l2 - 2.0f) < F_EPS;
    double ccp = z1 ? -1.0 : (double)l1 - 1.0;
    double ccn = z2 ? -1.0 : 1.0 - (double)l2;
    double ljb = ccp * sup + ccn * sun;
    double mean = s[j] / n;
    double var = s[6 + j] / n - mean * mean;
    var = var > 1e-12 ? var : 1e-12;
    scores[j] = n * (D_HALF_LOG2_2PIE + 0.5 * log2(var)) + ljb + D_LAMBDA_BITS;
  }
  double mn = scores[0];
#pragma unroll
  for (int j = 1; j < 6; ++j) mn = scores[j] < mn ? scores[j] : mn;
  double wsum = 0.0, b1 = 0.0, b2 = 0.0;
#pragma unroll
  for (int j = 0; j < 6; ++j) {
    double w = (scores[j] == mn) ? 1.0 : 0.0;
    wsum += w; b1 += w * al1[j]; b2 += w * al2[j];
  }
  bestL[2 * f]     = (float)(b1 / wsum);
  bestL[2 * f + 1] = (float)(b2 / wsum);
  tied[f] = (wsum > 1.5) ? 1 : 0;
  bitsF[f] = mn;   // unique min: identical to re-evaluating at best lambda
}

// Fallback pass 2 (only if some feature tied: averaged lambda is new).
__global__ __launch_bounds__(256) void k_pass2(
    const float* __restrict__ x, const float* __restrict__ bestL,
    const int* __restrict__ tied, float* __restrict__ P2)
{
  __shared__ int any;
  const int t = threadIdx.x;
  if (t == 0) any = 0;
  __syncthreads();
  if (tied[t]) any = 1;
  __syncthreads();
  if (!any) return;

  const int c = blockIdx.x;
  const int rpt = NROWS / CH2;   // 128
  const float l1 = bestL[2 * t], l2 = bestL[2 * t + 1];
  const bool z1 = fabsf(l1) < F_EPS;
  const bool z2 = fabsf(l2 - 2.0f) < F_EPS;
  const float tm = 2.0f - l2;
  const float a_p = z1 ? 0.f : l1,  s_pv = z1 ? 0.f : 1.f / l1,  t_pv = z1 ? F_LN2 : 0.f;
  const float a_n = z2 ? 0.f : tm,  s_nv = z2 ? 0.f : -1.f / tm, t_nv = z2 ? -F_LN2 : 0.f;

  float sy = 0.f, sq = 0.f;
  const float* xp = x + (size_t)c * rpt * NFEAT + t;
  for (int i = 0; i < rpt; ++i) {
    float v = xp[(size_t)i * NFEAT];
    bool pos = v >= 0.0f;
    float u2 = FAST_LOG2(1.0f + fabsf(v));
    float a  = pos ? a_p : a_n;
    float s  = pos ? s_pv : s_nv;
    float tt = pos ? t_pv : t_nv;
    float e = FAST_EXP2(a * u2);
    float y = fmaf(tt, u2, fmaf(s, e, -s));
    sy += y;
    sq = fmaf(y, y, sq);
  }
  P2[((size_t)c * 2 + 0) * NFEAT + t] = sy;
  P2[((size_t)c * 2 + 1) * NFEAT + t] = sq;
}

__global__ __launch_bounds__(64) void k_featbits(
    const float* __restrict__ P1, const float* __restrict__ P2,
    const float* __restrict__ bestL, const int* __restrict__ tied,
    double* __restrict__ bitsF, int CHv)
{
  const int f = blockIdx.x;
  if (!tied[f]) return;
  const int lane = threadIdx.x;
  double s0 = 0.0, s1 = 0.0, sup = 0.0, sua = 0.0;
  for (int c = lane; c < CH2; c += 64) {
    s0 += (double)P2[((size_t)c * 2 + 0) * NFEAT + f];
    s1 += (double)P2[((size_t)c * 2 + 1) * NFEAT + f];
  }
  for (int c = lane; c < CHv; c += 64) {
    sup += (double)P1[((size_t)c * 14 + 12) * NFEAT + f];
    sua += (double)P1[((size_t)c * 14 + 13) * NFEAT + f];
  }
  s0 = wave_reduce_add(s0); s1 = wave_reduce_add(s1);
  sup = wave_reduce_add(sup); sua = wave_reduce_add(sua);
  if (lane == 0) {
    const float l1 = bestL[2 * f], l2 = bestL[2 * f + 1];
    bool z1 = fabsf(l1) < F_EPS;
    bool z2 = fabsf(l2 - 2.0f) < F_EPS;
    double ccp = z1 ? -1.0 : (double)l1 - 1.0;
    double ccn = z2 ? -1.0 : 1.0 - (double)l2;
    double ljb = ccp * sup + ccn * (sua - sup);
    const double n = (double)NROWS;
    double mean = s0 / n;
    double var = s1 / n - mean * mean;
    var = var > 1e-12 ? var : 1e-12;
    bitsF[f] = n * (D_HALF_LOG2_2PIE + 0.5 * log2(var)) + ljb + D_LAMBDA_BITS;
  }
}

__global__ __launch_bounds__(256) void k_final(
    const double* __restrict__ bitsF, const double* __restrict__ pSums,
    float* __restrict__ out)
{
  __shared__ double l[4];
  double s = bitsF[threadIdx.x];
  s = wave_reduce_add(s);
  int w = threadIdx.x >> 6;
  if ((threadIdx.x & 63) == 0) l[w] = s;
  __syncthreads();
  if (threadIdx.x == 0) {
    double data = l[0] + l[1] + l[2] + l[3];
    const double n = (double)PCOUNT;
    double mean = pSums[0] / n;
    double var = pSums[1] / n - mean * mean;
    var = var > 1e-12 ? var : 1e-12;
    double model = n * (D_HALF_LOG2_2PIE + 0.5 * log2(var)) + D_LAMBDA_BITS;
    out[0] = (float)(data + model);
  }
}

extern "C" void kernel_launch(void* const* d_in, const int* in_sizes, int n_in,
                              void* d_out, int out_size, void* d_ws, size_t ws_size,
                              hipStream_t stream)
{
  const float* x      = (const float*)d_in[0];
  const float* lam1   = (const float*)d_in[1];
  const float* lam2   = (const float*)d_in[2];
  const float* rp     = (const float*)d_in[3];
  const float* params = (const float*)d_in[4];

  char* ws = (char*)d_ws;
  double* pSums = (double*)ws;                  // 16 B   -> 16
  float*  bestL = (float*)(ws + 16);            // 2048   -> 2064
  double* bitsF = (double*)(ws + 2064);         // 2048   -> 4112
  int*    tied  = (int*)(ws + 4112);            // 1024   -> 5136
  double* S2    = (double*)(ws + 5136);         // 14*8*256*8 = 229376 -> 234512
  float*  P1    = (float*)(ws + 234512);

  // adaptive chunk count: prefer CH=1024 (exactly 4 blocks/CU)
  int CHv = 1024;
  while (CHv > 256) {
    size_t need = 234512 + (size_t)CHv * 14 * NFEAT * 4
                         + (size_t)CH2 * 2 * NFEAT * 4;
    if (need <= ws_size) break;
    CHv >>= 1;
  }
  float* P2 = (float*)(ws + 234512 + (size_t)CHv * 14 * NFEAT * 4);
  int rpt = NROWS / CHv;

  (void)hipMemsetAsync(pSums, 0, 16, stream);
  k_pass1<<<CHv, 256, 0, stream>>>(x, lam1, lam2, rp, params, P1, pSums, CHv, rpt);
  k_reduce_S<<<14 * RGRP, 256, 0, stream>>>(P1, S2, CHv);
  k_pick<<<1, 256, 0, stream>>>(S2, lam1, lam2, rp, bestL, tied, bitsF);
  k_pass2<<<CH2, 256, 0, stream>>>(x, bestL, tied, P2);
  k_featbits<<<NFEAT, 64, 0, stream>>>(P1, P2, bestL, tied, bitsF, CHv);
  k_final<<<1, 256, 0, stream>>>(bitsF, pSums, (float*)d_out);
}

// Round 10
// 76.787 us; speedup vs baseline: 1.3667x; 1.1773x over previous
//
#include <hip/hip_runtime.h>
#include <math.h>

#define NFEAT 256
#define NROWS 65536
#define PCOUNT 4194304
#define PBLK 64                      // param-reduce blocks appended to pass1 grid
#define CH2 512                      // pass2 fallback chunks
#define RGRP 8                       // reduce_S c-groups
#define F_EPS 5.9604645e-07f         // float32 eps * 5
#define F_LN2 0.69314718056f

#define FAST_LOG2(v) __builtin_log2f(v)   // v_log_f32
#define FAST_EXP2(v) __builtin_exp2f(v)   // v_exp_f32

constexpr double D_HALF_LOG2_2PIE = 0.5 * 2.8378770664093453 / 0.6931471805599453;
constexpr double D_LAMBDA_BITS = 13.287712379549449; // 2*log2(100)

__device__ inline double wave_reduce_add(double v) {
  for (int o = 32; o > 0; o >>= 1) v += __shfl_down(v, o, 64);
  return v;
}

// ---------------------------------------------------------------------------
// Pass 1: 512-thread blocks; thread = (f = tid&255, half = tid>>8).
// half 0 computes proposals j=0..2, half 1 computes j=3..5, over the SAME
// rows [c*rpt,(c+1)*rpt). No cross-half reduction: halves own disjoint P1
// slots. Cost: log2 computed twice per element (8 trans vs 7) -- buys 2x
// thread-level parallelism at ~40 VGPR so 4 blocks/CU = 32 waves/CU.
// Partials: P1[(c*14+k)*NFEAT+f]; k 0..5 sum_y, 6..11 sum_y2,
// 12 sum_u2(pos), 13 sum_u2(all); u2 = log2(1+|x|).
// Blocks >= CHv: parameter tensor reduction (overlapped, memory-bound).
// ---------------------------------------------------------------------------
__global__ __launch_bounds__(512, 8) void k_pass1(
    const float* __restrict__ x, const float* __restrict__ lam1,
    const float* __restrict__ lam2, const float* __restrict__ rp,
    const float* __restrict__ params, float* __restrict__ P1,
    double* __restrict__ pSums, int CHv, int rpt)
{
  const int c = blockIdx.x;
  const int tid = threadIdx.x;

  if (c >= CHv) {
    // ---- parameter tensor partial reduction ----
    __shared__ double lred[2][8];
    const int b = c - CHv;
    const float4* p4 = (const float4*)params;
    double s = 0.0, q = 0.0;
    for (int i = b * 512 + tid; i < PCOUNT / 4; i += PBLK * 512) {
      float4 v = p4[i];
      s += (double)v.x + (double)v.y + (double)v.z + (double)v.w;
      q += (double)v.x * v.x + (double)v.y * v.y
         + (double)v.z * v.z + (double)v.w * v.w;
    }
    s = wave_reduce_add(s); q = wave_reduce_add(q);
    const int w = tid >> 6;
    if ((tid & 63) == 0) { lred[0][w] = s; lred[1][w] = q; }
    __syncthreads();
    if (tid == 0) {
      double S = 0.0, Q = 0.0;
#pragma unroll
      for (int i = 0; i < 8; ++i) { S += lred[0][i]; Q += lred[1][i]; }
      atomicAdd(&pSums[0], S);
      atomicAdd(&pSums[1], Q);
    }
    return;
  }

  const int f = tid & 255;
  const int half = tid >> 8;          // 0: j=0..2, 1: j=3..5
  __shared__ int bad;
  if (tid == 0) bad = 0;
  __syncthreads();

  const float L1 = lam1[f], L2 = lam2[f];
  float l1v[3], l2v[3];
  bool b = false;
#pragma unroll
  for (int m = 0; m < 3; ++m) {
    const int j = half * 3 + m;
    l1v[m] = (j == 0) ? L1 : L1 + 0.1f * rp[f * 10 + 2 * (j - 1)];
    l2v[m] = (j == 0) ? L2 : L2 + 0.1f * rp[f * 10 + 2 * (j - 1) + 1];
    b = b || (fabsf(l1v[m]) < F_EPS) || (fabsf(l2v[m] - 2.0f) < F_EPS);
  }
  if (b) bad = 1;  // benign same-value race
  __syncthreads();

  float as[3], aq[3];
#pragma unroll
  for (int m = 0; m < 3; ++m) { as[m] = 0.f; aq[m] = 0.f; }
  float u2p = 0.f, u2a = 0.f;
  const float* xp = x + (size_t)c * rpt * NFEAT + f;

  if (bad == 0) {
    // ---- simple path: 4-row groups, 12 indep exp chains per group ----
    float a_p[3], a_n[3], s_p[3], s_n[3];
#pragma unroll
    for (int m = 0; m < 3; ++m) {
      a_p[m] = l1v[m];
      a_n[m] = 2.0f - l2v[m];
      s_p[m] = 1.0f / a_p[m];
      s_n[m] = -1.0f / a_n[m];
    }
    for (int i = 0; i < rpt; i += 4) {
      float u[4]; bool pos[4];
#pragma unroll
      for (int r = 0; r < 4; ++r) {
        float v = xp[(size_t)(i + r) * NFEAT];
        pos[r] = v >= 0.0f;
        u[r] = FAST_LOG2(1.0f + fabsf(v));
        u2a += u[r];
        u2p += pos[r] ? u[r] : 0.0f;
      }
#pragma unroll
      for (int m = 0; m < 3; ++m) {
#pragma unroll
        for (int r = 0; r < 4; ++r) {
          float a = pos[r] ? a_p[m] : a_n[m];
          float s = pos[r] ? s_p[m] : s_n[m];
          float e = FAST_EXP2(a * u[r]);
          float y = fmaf(s, e, -s);    // s*(e-1)
          as[m] += y;
          aq[m] = fmaf(y, y, aq[m]);
        }
      }
    }
  } else {
    // ---- general path (lambda special cases) ----
    float ga_p[3], ga_n[3], gs_p[3], gs_n[3], gt_p[3], gt_n[3];
#pragma unroll
    for (int m = 0; m < 3; ++m) {
      float l1 = l1v[m];
      float tm = 2.0f - l2v[m];
      bool z1 = fabsf(l1) < F_EPS;
      bool z2 = fabsf(tm) < F_EPS;
      ga_p[m] = z1 ? 0.0f : l1;
      gs_p[m] = z1 ? 0.0f : 1.0f / l1;
      gt_p[m] = z1 ? F_LN2 : 0.0f;
      ga_n[m] = z2 ? 0.0f : tm;
      gs_n[m] = z2 ? 0.0f : -1.0f / tm;
      gt_n[m] = z2 ? -F_LN2 : 0.0f;
    }
    for (int i = 0; i < rpt; ++i) {
      float v = xp[(size_t)i * NFEAT];
      bool pos = v >= 0.0f;
      float u2 = FAST_LOG2(1.0f + fabsf(v));
      u2a += u2;
      u2p += pos ? u2 : 0.0f;
#pragma unroll
      for (int m = 0; m < 3; ++m) {
        float a  = pos ? ga_p[m] : ga_n[m];
        float s  = pos ? gs_p[m] : gs_n[m];
        float tt = pos ? gt_p[m] : gt_n[m];
        float e = FAST_EXP2(a * u2);
        float y = fmaf(tt, u2, fmaf(s, e, -s));
        as[m] += y;
        aq[m] = fmaf(y, y, aq[m]);
      }
    }
  }

#pragma unroll
  for (int m = 0; m < 3; ++m) {
    const int j = half * 3 + m;
    P1[((size_t)c * 14 + j) * NFEAT + f]     = as[m];
    P1[((size_t)c * 14 + 6 + j) * NFEAT + f] = aq[m];
  }
  if (half == 0) {
    P1[((size_t)c * 14 + 12) * NFEAT + f] = u2p;
    P1[((size_t)c * 14 + 13) * NFEAT + f] = u2a;
  }
}

// Stage A reduce: block (k, cg): S2[(k*RGRP+cg)*NFEAT+f] = sum over c-subrange.
__global__ __launch_bounds__(256) void k_reduce_S(
    const float* __restrict__ P1, double* __restrict__ S2, int CHv)
{
  const int k = blockIdx.x / RGRP;
  const int cg = blockIdx.x % RGRP;
  const int f = threadIdx.x;
  const int per = CHv / RGRP;
  const int c0 = cg * per;
  double a0 = 0.0, a1 = 0.0, a2 = 0.0, a3 = 0.0;
  for (int c = c0; c < c0 + per; c += 4) {
    a0 += (double)P1[((size_t)(c + 0) * 14 + k) * NFEAT + f];
    a1 += (double)P1[((size_t)(c + 1) * 14 + k) * NFEAT + f];
    a2 += (double)P1[((size_t)(c + 2) * 14 + k) * NFEAT + f];
    a3 += (double)P1[((size_t)(c + 3) * 14 + k) * NFEAT + f];
  }
  S2[((size_t)k * RGRP + cg) * NFEAT + f] = (a0 + a1) + (a2 + a3);
}

// One thread per feature: 6 scores in f64, min, tie-average.
__global__ __launch_bounds__(256) void k_pick(
    const double* __restrict__ S2, const float* __restrict__ lam1,
    const float* __restrict__ lam2, const float* __restrict__ rp,
    float* __restrict__ bestL, int* __restrict__ tied,
    double* __restrict__ bitsF)
{
  const int f = threadIdx.x;
  double s[14];
#pragma unroll
  for (int k = 0; k < 14; ++k) {
    double a = 0.0;
#pragma unroll
    for (int cg = 0; cg < RGRP; ++cg)
      a += S2[((size_t)k * RGRP + cg) * NFEAT + f];
    s[k] = a;
  }
  const double n = (double)NROWS;
  const double sup = s[12];
  const double sun = s[13] - s[12];
  const float L1 = lam1[f], L2 = lam2[f];
  double scores[6], al1[6], al2[6];
#pragma unroll
  for (int j = 0; j < 6; ++j) {
    float l1 = (j == 0) ? L1 : L1 + 0.1f * rp[f * 10 + 2 * (j - 1)];
    float l2 = (j == 0) ? L2 : L2 + 0.1f * rp[f * 10 + 2 * (j - 1) + 1];
    al1[j] = (double)l1; al2[j] = (double)l2;
    bool z1 = fabsf(l1) < F_EPS;
    bool z2 = fabsf(l2 - 2.0f) < F_EPS;
    double ccp = z1 ? -1.0 : (double)l1 - 1.0;
    double ccn = z2 ? -1.0 : 1.0 - (double)l2;
    double ljb = ccp * sup + ccn * sun;
    double mean = s[j] / n;
    double var = s[6 + j] / n - mean * mean;
    var = var > 1e-12 ? var : 1e-12;
    scores[j] = n * (D_HALF_LOG2_2PIE + 0.5 * log2(var)) + ljb + D_LAMBDA_BITS;
  }
  double mn = scores[0];
#pragma unroll
  for (int j = 1; j < 6; ++j) mn = scores[j] < mn ? scores[j] : mn;
  double wsum = 0.0, b1 = 0.0, b2 = 0.0;
#pragma unroll
  for (int j = 0; j < 6; ++j) {
    double w = (scores[j] == mn) ? 1.0 : 0.0;
    wsum += w; b1 += w * al1[j]; b2 += w * al2[j];
  }
  bestL[2 * f]     = (float)(b1 / wsum);
  bestL[2 * f + 1] = (float)(b2 / wsum);
  tied[f] = (wsum > 1.5) ? 1 : 0;
  bitsF[f] = mn;   // unique min: identical to re-evaluating at best lambda
}

// Fallback pass 2 (only if some feature tied: averaged lambda is new).
__global__ __launch_bounds__(256) void k_pass2(
    const float* __restrict__ x, const float* __restrict__ bestL,
    const int* __restrict__ tied, float* __restrict__ P2)
{
  __shared__ int any;
  const int t = threadIdx.x;
  if (t == 0) any = 0;
  __syncthreads();
  if (tied[t]) any = 1;
  __syncthreads();
  if (!any) return;

  const int c = blockIdx.x;
  const int rpt = NROWS / CH2;   // 128
  const float l1 = bestL[2 * t], l2 = bestL[2 * t + 1];
  const bool z1 = fabsf(l1) < F_EPS;
  const bool z2 = fabsf(l2 - 2.0f) < F_EPS;
  const float tm = 2.0f - l2;
  const float a_p = z1 ? 0.f : l1,  s_pv = z1 ? 0.f : 1.f / l1,  t_pv = z1 ? F_LN2 : 0.f;
  const float a_n = z2 ? 0.f : tm,  s_nv = z2 ? 0.f : -1.f / tm, t_nv = z2 ? -F_LN2 : 0.f;

  float sy = 0.f, sq = 0.f;
  const float* xp = x + (size_t)c * rpt * NFEAT + t;
  for (int i = 0; i < rpt; ++i) {
    float v = xp[(size_t)i * NFEAT];
    bool pos = v >= 0.0f;
    float u2 = FAST_LOG2(1.0f + fabsf(v));
    float a  = pos ? a_p : a_n;
    float s  = pos ? s_pv : s_nv;
    float tt = pos ? t_pv : t_nv;
    float e = FAST_EXP2(a * u2);
    float y = fmaf(tt, u2, fmaf(s, e, -s));
    sy += y;
    sq = fmaf(y, y, sq);
  }
  P2[((size_t)c * 2 + 0) * NFEAT + t] = sy;
  P2[((size_t)c * 2 + 1) * NFEAT + t] = sq;
}

__global__ __launch_bounds__(64) void k_featbits(
    const float* __restrict__ P1, const float* __restrict__ P2,
    const float* __restrict__ bestL, const int* __restrict__ tied,
    double* __restrict__ bitsF, int CHv)
{
  const int f = blockIdx.x;
  if (!tied[f]) return;
  const int lane = threadIdx.x;
  double s0 = 0.0, s1 = 0.0, sup = 0.0, sua = 0.0;
  for (int c = lane; c < CH2; c += 64) {
    s0 += (double)P2[((size_t)c * 2 + 0) * NFEAT + f];
    s1 += (double)P2[((size_t)c * 2 + 1) * NFEAT + f];
  }
  for (int c = lane; c < CHv; c += 64) {
    sup += (double)P1[((size_t)c * 14 + 12) * NFEAT + f];
    sua += (double)P1[((size_t)c * 14 + 13) * NFEAT + f];
  }
  s0 = wave_reduce_add(s0); s1 = wave_reduce_add(s1);
  sup = wave_reduce_add(sup); sua = wave_reduce_add(sua);
  if (lane == 0) {
    const float l1 = bestL[2 * f], l2 = bestL[2 * f + 1];
    bool z1 = fabsf(l1) < F_EPS;
    bool z2 = fabsf(l2 - 2.0f) < F_EPS;
    double ccp = z1 ? -1.0 : (double)l1 - 1.0;
    double ccn = z2 ? -1.0 : 1.0 - (double)l2;
    double ljb = ccp * sup + ccn * (sua - sup);
    const double n = (double)NROWS;
    double mean = s0 / n;
    double var = s1 / n - mean * mean;
    var = var > 1e-12 ? var : 1e-12;
    bitsF[f] = n * (D_HALF_LOG2_2PIE + 0.5 * log2(var)) + ljb + D_LAMBDA_BITS;
  }
}

__global__ __launch_bounds__(256) void k_final(
    const double* __restrict__ bitsF, const double* __restrict__ pSums,
    float* __restrict__ out)
{
  __shared__ double l[4];
  double s = bitsF[threadIdx.x];
  s = wave_reduce_add(s);
  int w = threadIdx.x >> 6;
  if ((threadIdx.x & 63) == 0) l[w] = s;
  __syncthreads();
  if (threadIdx.x == 0) {
    double data = l[0] + l[1] + l[2] + l[3];
    const double n = (double)PCOUNT;
    double mean = pSums[0] / n;
    double var = pSums[1] / n - mean * mean;
    var = var > 1e-12 ? var : 1e-12;
    double model = n * (D_HALF_LOG2_2PIE + 0.5 * log2(var)) + D_LAMBDA_BITS;
    out[0] = (float)(data + model);
  }
}

extern "C" void kernel_launch(void* const* d_in, const int* in_sizes, int n_in,
                              void* d_out, int out_size, void* d_ws, size_t ws_size,
                              hipStream_t stream)
{
  const float* x      = (const float*)d_in[0];
  const float* lam1   = (const float*)d_in[1];
  const float* lam2   = (const float*)d_in[2];
  const float* rp     = (const float*)d_in[3];
  const float* params = (const float*)d_in[4];

  char* ws = (char*)d_ws;
  double* pSums = (double*)ws;                  // 16 B   -> 16
  float*  bestL = (float*)(ws + 16);            // 2048   -> 2064
  double* bitsF = (double*)(ws + 2064);         // 2048   -> 4112
  int*    tied  = (int*)(ws + 4112);            // 1024   -> 5136
  double* S2    = (double*)(ws + 5136);         // 14*8*256*8 = 229376 -> 234512
  float*  P1    = (float*)(ws + 234512);

  // adaptive chunk count: prefer CH=1024 (4 blocks/CU of 512 threads)
  int CHv = 1024;
  while (CHv > 256) {
    size_t need = 234512 + (size_t)CHv * 14 * NFEAT * 4
                         + (size_t)CH2 * 2 * NFEAT * 4;
    if (need <= ws_size) break;
    CHv >>= 1;
  }
  float* P2 = (float*)(ws + 234512 + (size_t)CHv * 14 * NFEAT * 4);
  int rpt = NROWS / CHv;

  (void)hipMemsetAsync(pSums, 0, 16, stream);
  k_pass1<<<CHv + PBLK, 512, 0, stream>>>(x, lam1, lam2, rp, params, P1,
                                          pSums, CHv, rpt);
  k_reduce_S<<<14 * RGRP, 256, 0, stream>>>(P1, S2, CHv);
  k_pick<<<1, 256, 0, stream>>>(S2, lam1, lam2, rp, bestL, tied, bitsF);
  k_pass2<<<CH2, 256, 0, stream>>>(x, bestL, tied, P2);
  k_featbits<<<NFEAT, 64, 0, stream>>>(P1, P2, bestL, tied, bitsF, CHv);
  k_final<<<1, 256, 0, stream>>>(bitsF, pSums, (float*)d_out);
}